// Round 7
// baseline (3263.363 us; speedup 1.0000x reference)
//
#include <hip/hip_runtime.h>

#define TPB 256
#define NBLK 256
#define SPIN_BOUND (1u << 21)

typedef _Float16 h8 __attribute__((ext_vector_type(8)));
typedef float f4 __attribute__((ext_vector_type(4)));

__device__ __forceinline__ float sigf(float x) { return 1.f / (1.f + __expf(-x)); }
__device__ __forceinline__ float tanhfast(float x) { return 2.f / (1.f + __expf(-2.f * x)) - 1.f; }

#define MF(acc, a, b) acc = __builtin_amdgcn_mfma_f32_16x16x32_f16(a, b, acc, 0, 0, 0)

__device__ __forceinline__ void vm0() { asm volatile("s_waitcnt vmcnt(0)" ::: "memory"); }
__device__ __forceinline__ void l1inv() { asm volatile("buffer_inv sc0" ::: "memory"); }

// ---- XCD-L2-local flag sync, using the PROVEN data-path mechanism:
// producer: plain store (write-through L1 -> shared XCD L2), ordered after h
//           stores by a preceding s_waitcnt vmcnt(0);
// consumer: buffer_inv sc0 (CU-L1 invalidate) + plain volatile load each poll
//           iteration -> always observes current L2 content.
// (Round 4/6 lesson: sc0/plain LOADS without inv can hit stale L1 forever;
//  rounds 3/5 proved inv+load reads fresh same-XCD L2 data every step.)
__device__ __forceinline__ void fl_st(unsigned* p, unsigned v) {
    *(volatile unsigned*)p = v;
}
// bounded spin; false on timeout (sync failure -> fast wrong answer, not hang)
__device__ __forceinline__ bool poll_ge(const unsigned* p, unsigned target) {
    const volatile unsigned* vp = (const volatile unsigned*)p;
    unsigned n = 0;
    for (;;) {
        l1inv();
        if (*vp >= target) return true;
        __builtin_amdgcn_s_sleep(1);
        if (++n > SPIN_BOUND) return false;
    }
}
// wave-parallel wait on a 32-flag line (lanes 32-63 duplicate 0-31)
__device__ __forceinline__ void wait_flags(const unsigned* line, unsigned target, int lane, bool& dead) {
    if (dead) return;
    const volatile unsigned* p = (const volatile unsigned*)(line + (lane & 31));
    unsigned n = 0;
    for (;;) {
        l1inv();
        unsigned v = *p;
        if (__all((int)(v >= target))) return;
        __builtin_amdgcn_s_sleep(1);
        if (++n > SPIN_BOUND) { dead = true; return; }
    }
}

// ---------------------------------------------------------------- prep kernels

__global__ void prep_conv(const float* __restrict__ in, const float* __restrict__ mlpw,
                          const float* __restrict__ adpw,
                          _Float16* __restrict__ seqX, _Float16* __restrict__ mlpW16,
                          _Float16* __restrict__ adpW16)
{
    const int NIN = 256 * 128 * 128;
    const int NM = 512 * 512;
    const int NA = 48 * 512;
    int i = blockIdx.x * blockDim.x + threadIdx.x;
    const int stride = gridDim.x * blockDim.x;
    for (; i < NIN + NM + NA; i += stride) {
        if (i < NIN) seqX[i] = (_Float16)in[i];
        else if (i < NIN + NM) mlpW16[i - NIN] = (_Float16)mlpw[i - NIN];
        else adpW16[i - NIN - NM] = (_Float16)adpw[i - NIN - NM];
    }
}

__global__ void prep_bias(const float* __restrict__ a0, const float* __restrict__ b0,
                          const float* __restrict__ a1, const float* __restrict__ b1,
                          const float* __restrict__ a2, const float* __restrict__ b2,
                          const float* __restrict__ a3, const float* __restrict__ b3,
                          float* __restrict__ biasSum)
{
    int i = blockIdx.x * blockDim.x + threadIdx.x;
    if (i >= 8192) return;
    const int c = i >> 11, j = i & 2047;
    const float* A = (c == 0) ? a0 : (c == 1) ? a1 : (c == 2) ? a2 : a3;
    const float* B = (c == 0) ? b0 : (c == 1) ? b1 : (c == 2) ? b2 : b3;
    biasSum[i] = A[j] + B[j];
}

// Wprep layout per cell: [p=32 col-groups][64 rows][K] fp16
__global__ void prep_w(const float* __restrict__ wih0, const float* __restrict__ whh0,
                       const float* __restrict__ wih1, const float* __restrict__ whh1,
                       const float* __restrict__ wih2, const float* __restrict__ whh2,
                       const float* __restrict__ wih3, const float* __restrict__ whh3,
                       _Float16* __restrict__ Wprep)
{
    const size_t N0 = (size_t)2048 * 640;
    const size_t N1 = (size_t)2048 * 1024;
    const size_t total = N0 + 3 * N1;
    size_t i = (size_t)blockIdx.x * blockDim.x + threadIdx.x;
    const size_t stride = (size_t)gridDim.x * blockDim.x;
    for (; i < total; i += stride) {
        int cell; size_t off;
        if (i < N0) { cell = 0; off = i; }
        else { cell = 1 + (int)((i - N0) / N1); off = (i - N0) % N1; }
        const int K = cell ? 1024 : 640;
        const int Din = cell ? 512 : 128;
        const int k = (int)(off % K);
        const int rowIdx = (int)(off / K);
        const int p = rowIdx >> 6;
        const int row64 = rowIdx & 63;
        const int q = row64 >> 4;
        const int gRow = q * 512 + p * 16 + (row64 & 15);
        const float* wih = (cell == 0) ? wih0 : (cell == 1) ? wih1 : (cell == 2) ? wih2 : wih3;
        const float* whh = (cell == 0) ? whh0 : (cell == 1) ? whh1 : (cell == 2) ? whh2 : whh3;
        const float v = (k < Din) ? wih[(size_t)gRow * Din + k]
                                  : whh[(size_t)gRow * 512 + (k - Din)];
        Wprep[i] = (_Float16)v;
    }
}

// ---------------------------------------------------------------- per-cell LSTM

template<int CELL>
__device__ __forceinline__ void run_cell(
    const _Float16* __restrict__ src, _Float16* __restrict__ dst,
    const _Float16* __restrict__ wbase, const float* __restrict__ biasSum,
    unsigned* __restrict__ flags, const unsigned genBase, char* smem,
    const int p, const int tid, const int lane, const int wave, const int rg)
{
    constexpr int Din = (CELL == 0) ? 128 : 512;
    constexpr int K = Din + 512;
    constexpr int Bd = 128 << CELL;
    constexpr int Td = 256 >> CELL;
    constexpr int r = Bd >> 3;
    constexpr int nMt = r >> 4;          // 1,2,4,8 m-tiles (4 waves; CELL3 = 2 tiles/wave)
    constexpr int ldsRow = K * 2;
    constexpr bool M2 = (CELL == 3);
    constexpr int NKX = Din >> 5;

    const int colsel = lane & 15;
    const int kq = lane >> 4;
    const int rowBase = rg * r;

    // stage W slice (64 rows x K fp16) into LDS, XOR-swizzled (all threads)
    {
        const _Float16* wsl = wbase + (size_t)p * 64 * K;
        constexpr int kcN = K >> 3;
        #pragma unroll 2
        for (int i = tid; i < 64 * kcN; i += TPB) {
            const int row = i / kcN;
            const int kc = i - row * kcN;
            h8 v = *(const h8*)(wsl + (size_t)row * K + (kc << 3));
            *(h8*)(smem + row * ldsRow + ((kc << 4) ^ ((row & 7) << 4))) = v;
        }
    }
    __syncthreads();   // W staged

    const bool has0 = (wave < nMt);
    if (!has0) return;   // idle waves go wait at the cell barrier

    const float bq0 = biasSum[CELL * 2048 + 0 * 512 + p * 16 + colsel];
    const float bq1 = biasSum[CELL * 2048 + 1 * 512 + p * 16 + colsel];
    const float bq2 = biasSum[CELL * 2048 + 2 * 512 + p * 16 + colsel];
    const float bq3 = biasSum[CELL * 2048 + 3 * 512 + p * 16 + colsel];

    const int arow0 = rowBase + wave * 16 + colsel;
    const int arow1 = rowBase + (wave + 4) * 16 + colsel;
    const int hcol = p * 16 + colsel;

    unsigned* myFlagLine = flags + (rg * 4 + wave) * 32;
    unsigned* myFlag = myFlagLine + p;

    float cr0[4] = {0.f, 0.f, 0.f, 0.f};
    float cr1[4] = {0.f, 0.f, 0.f, 0.f};
    bool dead = false;

    auto ldB = [&](int kbyte, int rrow) -> h8 {
        return *(const h8*)(smem + rrow * ldsRow + (kbyte ^ ((rrow & 7) << 4)));
    };

    auto xpart = [&](int t, f4 (&A0)[4], f4 (&A1)[4]) {
        #pragma unroll
        for (int g = 0; g < 4; ++g) {
            A0[g] = (f4){0.f, 0.f, 0.f, 0.f};
            if constexpr (M2) A1[g] = (f4){0.f, 0.f, 0.f, 0.f};
        }
        const _Float16* xb = src + (size_t)t * Bd * Din;
        const _Float16* a0p = xb + (size_t)arow0 * Din;
        const _Float16* a1p = xb + (size_t)arow1 * Din;
        #pragma unroll
        for (int ks = 0; ks < NKX; ++ks) {
            const int kb = (ks << 5) + (kq << 3);
            const int kbyte = kb << 1;
            h8 bf0 = ldB(kbyte, colsel);
            h8 bf1 = ldB(kbyte, 16 + colsel);
            h8 bf2 = ldB(kbyte, 32 + colsel);
            h8 bf3 = ldB(kbyte, 48 + colsel);
            h8 a0 = *(const h8*)(a0p + kb);
            MF(A0[0], a0, bf0); MF(A0[1], a0, bf1); MF(A0[2], a0, bf2); MF(A0[3], a0, bf3);
            if constexpr (M2) {
                h8 a1 = *(const h8*)(a1p + kb);
                MF(A1[0], a1, bf0); MF(A1[1], a1, bf1); MF(A1[2], a1, bf2); MF(A1[3], a1, bf3);
            }
        }
    };

    auto hpart = [&](int t, f4 (&A0)[4], f4 (&A1)[4]) {
        const _Float16* hb = dst + (size_t)(t - 1) * Bd * 512;
        const _Float16* a0p = hb + (size_t)arow0 * 512;
        const _Float16* a1p = hb + (size_t)arow1 * 512;
        #pragma unroll 4
        for (int ks = 0; ks < 16; ++ks) {
            const int kb = (ks << 5) + (kq << 3);
            const int kbyte = (Din + kb) << 1;
            h8 bf0 = ldB(kbyte, colsel);
            h8 bf1 = ldB(kbyte, 16 + colsel);
            h8 bf2 = ldB(kbyte, 32 + colsel);
            h8 bf3 = ldB(kbyte, 48 + colsel);
            h8 a0 = *(const h8*)(a0p + kb);
            MF(A0[0], a0, bf0); MF(A0[1], a0, bf1); MF(A0[2], a0, bf2); MF(A0[3], a0, bf3);
            if constexpr (M2) {
                h8 a1 = *(const h8*)(a1p + kb);
                MF(A1[0], a1, bf0); MF(A1[1], a1, bf1); MF(A1[2], a1, bf2); MF(A1[3], a1, bf3);
            }
        }
    };

    auto epilog = [&](int t, f4 (&A)[4], float (&cr)[4], int mt) {
        const size_t rb = (size_t)t * Bd + rowBase + mt * 16 + kq * 4;
        #pragma unroll
        for (int j = 0; j < 4; ++j) {
            const float gi = A[0][j] + bq0;
            const float gf = A[1][j] + bq1;
            const float gg = A[2][j] + bq2;
            const float go = A[3][j] + bq3;
            const float cc = sigf(gf) * cr[j] + sigf(gi) * tanhfast(gg);
            const float hh = sigf(go) * tanhfast(cc);
            cr[j] = cc;
            dst[(rb + j) * 512 + hcol] = (_Float16)hh;
        }
    };

    f4 A0[4], A1[4], B0[4], B1[4];
    xpart(0, A0, A1);

    // barrier-free per-wave dataflow step
    #define DR_STEP(T, C0, C1, N0, N1)                                       \
    {                                                                        \
        if ((T) > 0) {                                                       \
            wait_flags(myFlagLine, genBase + (unsigned)(T), lane, dead);     \
            l1inv();                                                         \
            hpart((T), C0, C1);                                              \
        }                                                                    \
        epilog((T), C0, cr0, wave);                                          \
        if constexpr (M2) epilog((T), C1, cr1, wave + 4);                    \
        vm0();                                                               \
        if (lane == 0) fl_st(myFlag, genBase + (unsigned)(T) + 1u);          \
        if ((T) + 1 < Td) xpart((T) + 1, N0, N1);                            \
    }

    for (int t = 0; t < Td; t += 2) {
        DR_STEP(t, A0, A1, B0, B1)
        DR_STEP(t + 1, B0, B1, A0, A1)
    }
    #undef DR_STEP
}

// ---------------------------------------------------------------- persistent kernel

__global__ __launch_bounds__(TPB) void drnn_persist(
    const _Float16* __restrict__ seqX,
    _Float16* __restrict__ seq0,
    _Float16* __restrict__ seq1,
    _Float16* __restrict__ seq2,
    _Float16* __restrict__ seq3,
    const _Float16* __restrict__ Wprep,
    const float* __restrict__ biasSum,
    unsigned* __restrict__ syncc)
{
    extern __shared__ char smem[];
    const int tid = threadIdx.x;
    const int lane = tid & 63;
    const int wave = tid >> 6;

    // Self-assign (rg, p) from physical XCD so each row-group's 32 blocks share
    // one L2. 128KB LDS -> 1 block/CU; 256 blocks on 256 CUs -> exactly 32/XCD.
    unsigned* s_flag = (unsigned*)smem;
    if (tid == 0) {
        unsigned xcc;
        asm volatile("s_getreg_b32 %0, hwreg(HW_REG_XCC_ID)" : "=s"(xcc));
        xcc &= 7u;
        unsigned slot = __hip_atomic_fetch_add(syncc + 64u * (9u + xcc), 1u,
                                               __ATOMIC_RELAXED, __HIP_MEMORY_SCOPE_AGENT);
        s_flag[0] = (xcc << 5) | (slot & 31u);
    }
    __syncthreads();
    const unsigned rgp = s_flag[0];
    __syncthreads();
    const int rg = rgp >> 5;     // == XCC_ID
    const int p = rgp & 31;      // col-group: h-cols [p*16, p*16+16)

    unsigned* cellCnt = syncc;             // dword 0
    unsigned* flags = syncc + 1024;        // 8rg x 4w x 32q dwords (4KB), line per (rg,w)

    // cross-XCD cell barrier (4x total): leader verifies rg completion via flags,
    // then agent-scope release/acquire moves h data across XCD L2s.
    auto cell_barrier = [&](int cellIdx, unsigned endGen, int nWprev) {
        __syncthreads();
        if (p == 0 && tid < 32 * nWprev) {
            const unsigned* fp = flags + (rg * 4 + (tid >> 5)) * 32 + (tid & 31);
            poll_ge(fp, endGen);
        }
        __syncthreads();
        if (tid == 0) {
            if (p == 0)
                __hip_atomic_fetch_add(cellCnt, 1u, __ATOMIC_RELEASE, __HIP_MEMORY_SCOPE_AGENT);
            unsigned n = 0;
            while (__hip_atomic_load(cellCnt, __ATOMIC_RELAXED, __HIP_MEMORY_SCOPE_AGENT)
                   < (unsigned)(8 * cellIdx)) {
                __builtin_amdgcn_s_sleep(2);
                if (++n > SPIN_BOUND) break;
            }
            (void)__hip_atomic_load(cellCnt, __ATOMIC_ACQUIRE, __HIP_MEMORY_SCOPE_AGENT);
        }
        __syncthreads();
        l1inv();
    };

    run_cell<0>(seqX, seq0, Wprep, biasSum, flags, 0u, smem, p, tid, lane, wave, rg);
    cell_barrier(1, 256u, 1);
    run_cell<1>(seq0, seq1, Wprep + (size_t)2048 * 640, biasSum, flags, 256u, smem, p, tid, lane, wave, rg);
    cell_barrier(2, 384u, 2);
    run_cell<2>(seq1, seq2, Wprep + (size_t)2048 * (640 + 1024), biasSum, flags, 384u, smem, p, tid, lane, wave, rg);
    cell_barrier(3, 448u, 4);
    run_cell<3>(seq2, seq3, Wprep + (size_t)2048 * (640 + 2048), biasSum, flags, 448u, smem, p, tid, lane, wave, rg);
}

// ---------------------------------------------------------------- head

__global__ __launch_bounds__(TPB) void head_kernel(
    const _Float16* __restrict__ seq1,
    const _Float16* __restrict__ seq3,
    const _Float16* __restrict__ mlpW16,
    const float* __restrict__ mlp_b,
    const _Float16* __restrict__ adpW16,
    const float* __restrict__ adp_b,
    float* __restrict__ out)
{
    extern __shared__ char smem[];   // y1 tile [64][512] fp16, XOR-swizzled
    const int tid = threadIdx.x;
    const int lane = tid & 63, wave = tid >> 6;
    const int colsel = lane & 15, kq = lane >> 4;
    const size_t row0 = (size_t)blockIdx.x * 64 + wave * 16;

    h8 aR[16];
    {
        const size_t ar = (row0 + colsel) * 512;
        #pragma unroll
        for (int ks = 0; ks < 16; ++ks) {
            const int kb = ks * 32 + kq * 8;
            h8 a1 = *(const h8*)(seq1 + ar + kb);
            h8 a3 = *(const h8*)(seq3 + ar + kb);
            aR[ks] = a1 + a3;
        }
    }
    for (int nt = 0; nt < 32; ++nt) {
        f4 acc = {0.f, 0.f, 0.f, 0.f};
        const int brow = nt * 16 + colsel;
        #pragma unroll
        for (int ks = 0; ks < 16; ++ks) {
            const int kb = ks * 32 + kq * 8;
            h8 b = *(const h8*)(mlpW16 + (size_t)brow * 512 + kb);
            acc = __builtin_amdgcn_mfma_f32_16x16x32_f16(aR[ks], b, acc, 0, 0, 0);
        }
        const int n = nt * 16 + colsel;
        const float bn = mlp_b[n];
        const int lrow0 = wave * 16 + kq * 4;
        #pragma unroll
        for (int j = 0; j < 4; ++j) {
            const float y = tanhfast(acc[j] + bn);
            const int row = lrow0 + j;
            *(_Float16*)(smem + row * 1024 + ((n * 2) ^ ((row & 7) << 4))) = (_Float16)y;
        }
    }
    __syncthreads();
    f4 acc0 = {0.f,0.f,0.f,0.f}, acc1 = {0.f,0.f,0.f,0.f}, acc2 = {0.f,0.f,0.f,0.f};
    const int arow = wave * 16 + colsel;
    #pragma unroll
    for (int ks = 0; ks < 16; ++ks) {
        const int kb = ks * 32 + kq * 8;
        h8 a = *(const h8*)(smem + arow * 1024 + ((kb * 2) ^ ((arow & 7) << 4)));
        h8 b0 = *(const h8*)(adpW16 + (size_t)(colsel) * 512 + kb);
        h8 b1 = *(const h8*)(adpW16 + (size_t)(16 + colsel) * 512 + kb);
        h8 b2 = *(const h8*)(adpW16 + (size_t)(32 + colsel) * 512 + kb);
        acc0 = __builtin_amdgcn_mfma_f32_16x16x32_f16(a, b0, acc0, 0, 0, 0);
        acc1 = __builtin_amdgcn_mfma_f32_16x16x32_f16(a, b1, acc1, 0, 0, 0);
        acc2 = __builtin_amdgcn_mfma_f32_16x16x32_f16(a, b2, acc2, 0, 0, 0);
    }
    const size_t orow0 = row0 + kq * 4;
    #pragma unroll
    for (int j = 0; j < 4; ++j) {
        out[(orow0 + j) * 48 + colsel]      = acc0[j] + adp_b[colsel];
        out[(orow0 + j) * 48 + 16 + colsel] = acc1[j] + adp_b[16 + colsel];
        out[(orow0 + j) * 48 + 32 + colsel] = acc2[j] + adp_b[32 + colsel];
    }
}

// ---------------------------------------------------------------- launch

extern "C" void kernel_launch(void* const* d_in, const int* in_sizes, int n_in,
                              void* d_out, int out_size, void* d_ws, size_t ws_size,
                              hipStream_t stream)
{
    (void)in_sizes; (void)n_in; (void)out_size; (void)ws_size;
    const float* input = (const float*)d_in[0];
    const float* Wih[4]; const float* Whh[4]; const float* Bih[4]; const float* Bhh[4];
    for (int i = 0; i < 4; ++i) {
        Wih[i] = (const float*)d_in[1 + 4 * i];
        Whh[i] = (const float*)d_in[2 + 4 * i];
        Bih[i] = (const float*)d_in[3 + 4 * i];
        Bhh[i] = (const float*)d_in[4 + 4 * i];
    }
    const float* mlpw = (const float*)d_in[17];
    const float* mlpb = (const float*)d_in[18];
    const float* adpw = (const float*)d_in[19];
    const float* adpb = (const float*)d_in[20];
    float* out = (float*)d_out;

    char* ws = (char*)d_ws;
    size_t off = 0;
    auto alloc = [&](size_t bytes) -> char* {
        char* ptr = ws + off;
        off += (bytes + 255) & ~(size_t)255;
        return ptr;
    };
    unsigned* syncc   = (unsigned*)alloc(16384);
    _Float16* seqX    = (_Float16*)alloc((size_t)32768 * 128 * 2);
    _Float16* seq0    = (_Float16*)alloc((size_t)32768 * 512 * 2);
    _Float16* seq1    = (_Float16*)alloc((size_t)32768 * 512 * 2);
    _Float16* seq2    = (_Float16*)alloc((size_t)32768 * 512 * 2);
    _Float16* seq3    = (_Float16*)alloc((size_t)32768 * 512 * 2);
    _Float16* Wprep   = (_Float16*)alloc((size_t)2048 * 3712 * 2);
    float*    biasSum = (float*)alloc(8192 * 4);
    _Float16* mlpW16  = (_Float16*)alloc((size_t)262144 * 2);
    _Float16* adpW16  = (_Float16*)alloc((size_t)24576 * 2);

    hipMemsetAsync(syncc, 0, 16384, stream);
    prep_conv<<<2048, 256, 0, stream>>>(input, mlpw, adpw, seqX, mlpW16, adpW16);
    prep_bias<<<32, 256, 0, stream>>>(Bih[0], Bhh[0], Bih[1], Bhh[1],
                                      Bih[2], Bhh[2], Bih[3], Bhh[3], biasSum);
    prep_w<<<4096, 256, 0, stream>>>(Wih[0], Whh[0], Wih[1], Whh[1],
                                     Wih[2], Whh[2], Wih[3], Whh[3], Wprep);

    hipFuncSetAttribute((const void*)drnn_persist,
                        hipFuncAttributeMaxDynamicSharedMemorySize, 131072);
    hipFuncSetAttribute((const void*)head_kernel,
                        hipFuncAttributeMaxDynamicSharedMemorySize, 65536);

    drnn_persist<<<NBLK, TPB, 131072, stream>>>(seqX, seq0, seq1, seq2, seq3,
                                                Wprep, biasSum, syncc);
    head_kernel<<<512, TPB, 65536, stream>>>(seq1, seq3, mlpW16, mlpb, adpW16, adpb, out);
}

// Round 8
// 2762.967 us; speedup vs baseline: 1.1811x; 1.1811x over previous
//
#include <hip/hip_runtime.h>

#define TPB 512
#define NBLK 256
#define SPIN_BOUND (1u << 21)

typedef _Float16 h8 __attribute__((ext_vector_type(8)));
typedef float f4 __attribute__((ext_vector_type(4)));

__device__ __forceinline__ float sigf(float x) { return 1.f / (1.f + __expf(-x)); }
__device__ __forceinline__ float tanhfast(float x) { return 2.f / (1.f + __expf(-2.f * x)) - 1.f; }

#define MF(acc, a, b) acc = __builtin_amdgcn_mfma_f32_16x16x32_f16(a, b, acc, 0, 0, 0)

__device__ __forceinline__ void vm0() { asm volatile("s_waitcnt vmcnt(0)" ::: "memory"); }
__device__ __forceinline__ void l1inv() { asm volatile("buffer_inv sc0" ::: "memory"); }

// Proven XCD-L2-local flag sync (round 7): producer = plain store after vmcnt(0)
// (write-through L1 -> shared XCD L2); consumer = buffer_inv sc0 + volatile load
// per poll iteration. All step-flag traffic stays in the XCD's L2.
__device__ __forceinline__ void fl_st(unsigned* p, unsigned v) {
    *(volatile unsigned*)p = v;
}
__device__ __forceinline__ bool poll_ge(const unsigned* p, unsigned target) {
    const volatile unsigned* vp = (const volatile unsigned*)p;
    unsigned n = 0;
    for (;;) {
        l1inv();
        if (*vp >= target) return true;
        __builtin_amdgcn_s_sleep(1);
        if (++n > SPIN_BOUND) return false;
    }
}
// wave-parallel wait on a 32-flag line (lanes 32-63 duplicate 0-31)
__device__ __forceinline__ void wait_flags(const unsigned* line, unsigned target, int lane, bool& dead) {
    if (dead) return;
    const volatile unsigned* p = (const volatile unsigned*)(line + (lane & 31));
    unsigned n = 0;
    for (;;) {
        l1inv();
        unsigned v = *p;
        if (__all((int)(v >= target))) return;
        __builtin_amdgcn_s_sleep(1);
        if (++n > SPIN_BOUND) { dead = true; return; }
    }
}

// ---------------------------------------------------------------- prep kernels

__global__ void prep_conv(const float* __restrict__ in, const float* __restrict__ mlpw,
                          const float* __restrict__ adpw,
                          _Float16* __restrict__ seqX, _Float16* __restrict__ mlpW16,
                          _Float16* __restrict__ adpW16)
{
    const int NIN = 256 * 128 * 128;
    const int NM = 512 * 512;
    const int NA = 48 * 512;
    int i = blockIdx.x * blockDim.x + threadIdx.x;
    const int stride = gridDim.x * blockDim.x;
    for (; i < NIN + NM + NA; i += stride) {
        if (i < NIN) seqX[i] = (_Float16)in[i];
        else if (i < NIN + NM) mlpW16[i - NIN] = (_Float16)mlpw[i - NIN];
        else adpW16[i - NIN - NM] = (_Float16)adpw[i - NIN - NM];
    }
}

__global__ void prep_bias(const float* __restrict__ a0, const float* __restrict__ b0,
                          const float* __restrict__ a1, const float* __restrict__ b1,
                          const float* __restrict__ a2, const float* __restrict__ b2,
                          const float* __restrict__ a3, const float* __restrict__ b3,
                          float* __restrict__ biasSum)
{
    int i = blockIdx.x * blockDim.x + threadIdx.x;
    if (i >= 8192) return;
    const int c = i >> 11, j = i & 2047;
    const float* A = (c == 0) ? a0 : (c == 1) ? a1 : (c == 2) ? a2 : a3;
    const float* B = (c == 0) ? b0 : (c == 1) ? b1 : (c == 2) ? b2 : b3;
    biasSum[i] = A[j] + B[j];
}

// Wprep layout per cell: [p=32 col-groups][64 rows][K] fp16
__global__ void prep_w(const float* __restrict__ wih0, const float* __restrict__ whh0,
                       const float* __restrict__ wih1, const float* __restrict__ whh1,
                       const float* __restrict__ wih2, const float* __restrict__ whh2,
                       const float* __restrict__ wih3, const float* __restrict__ whh3,
                       _Float16* __restrict__ Wprep)
{
    const size_t N0 = (size_t)2048 * 640;
    const size_t N1 = (size_t)2048 * 1024;
    const size_t total = N0 + 3 * N1;
    size_t i = (size_t)blockIdx.x * blockDim.x + threadIdx.x;
    const size_t stride = (size_t)gridDim.x * blockDim.x;
    for (; i < total; i += stride) {
        int cell; size_t off;
        if (i < N0) { cell = 0; off = i; }
        else { cell = 1 + (int)((i - N0) / N1); off = (i - N0) % N1; }
        const int K = cell ? 1024 : 640;
        const int Din = cell ? 512 : 128;
        const int k = (int)(off % K);
        const int rowIdx = (int)(off / K);
        const int p = rowIdx >> 6;
        const int row64 = rowIdx & 63;
        const int q = row64 >> 4;
        const int gRow = q * 512 + p * 16 + (row64 & 15);
        const float* wih = (cell == 0) ? wih0 : (cell == 1) ? wih1 : (cell == 2) ? wih2 : wih3;
        const float* whh = (cell == 0) ? whh0 : (cell == 1) ? whh1 : (cell == 2) ? whh2 : whh3;
        const float v = (k < Din) ? wih[(size_t)gRow * Din + k]
                                  : whh[(size_t)gRow * 512 + (k - Din)];
        Wprep[i] = (_Float16)v;
    }
}

// ---------------------------------------------------------------- per-cell LSTM
// 8 waves/block. Cells 0-2: each m-tile owned by a wave PAIR split over K
// (kh=0 / kh=1); kh=1 writes its partial accs to LDS scratch, one barrier,
// kh=0 reduces + epilog + h-store + flag. Cell 3: 8 m-tiles -> 1 per wave,
// full K, no reduce, no per-step barrier.

template<int CELL>
__device__ __forceinline__ void run_cell(
    const _Float16* __restrict__ src, _Float16* __restrict__ dst,
    const _Float16* __restrict__ wbase, const float* __restrict__ biasSum,
    unsigned* __restrict__ cellFlags, char* smem,
    const int p, const int tid, const int lane, const int wave, const int rg)
{
    constexpr int Din = (CELL == 0) ? 128 : 512;
    constexpr int K = Din + 512;
    constexpr int Bd = 128 << CELL;
    constexpr int Td = 256 >> CELL;
    constexpr int r = Bd >> 3;
    constexpr int nMt = r >> 4;          // m-tiles per block: 1,2,4,8
    constexpr int ldsRow = K * 2;
    constexpr int NKX = Din >> 5;        // 4 or 16
    constexpr bool RED = (CELL < 3);     // K-split + LDS reduce

    const int colsel = lane & 15;
    const int kq = lane >> 4;
    const int rowBase = rg * r;

    // stage W slice (64 rows x K fp16) into LDS, XOR-swizzled (all 512 threads)
    {
        const _Float16* wsl = wbase + (size_t)p * 64 * K;
        constexpr int kcN = K >> 3;
        #pragma unroll 2
        for (int i = tid; i < 64 * kcN; i += TPB) {
            const int row = i / kcN;
            const int kc = i - row * kcN;
            h8 v = *(const h8*)(wsl + (size_t)row * K + (kc << 3));
            *(h8*)(smem + row * ldsRow + ((kc << 4) ^ ((row & 7) << 4))) = v;
        }
    }
    __syncthreads();   // W staged

    const int mt = RED ? (wave >> 1) : wave;
    const int kh = RED ? (wave & 1) : 0;
    const bool busy = RED ? (wave < 2 * nMt) : true;

    // K ranges: kh=0 -> x-ks [0,NKX/2) + h-ks [0,8); kh=1 -> rest. cell3: full.
    const int xlo = (RED && kh) ? (NKX / 2) : 0;
    const int xhi = (RED && !kh) ? (NKX / 2) : NKX;
    const int hlo = (RED && kh) ? 8 : 0;
    const int hhi = (RED && !kh) ? 8 : 16;

    const float bq0 = biasSum[CELL * 2048 + 0 * 512 + p * 16 + colsel];
    const float bq1 = biasSum[CELL * 2048 + 1 * 512 + p * 16 + colsel];
    const float bq2 = biasSum[CELL * 2048 + 2 * 512 + p * 16 + colsel];
    const float bq3 = biasSum[CELL * 2048 + 3 * 512 + p * 16 + colsel];

    const int arow = rowBase + mt * 16 + colsel;
    const int hcol = p * 16 + colsel;

    unsigned* line = cellFlags + (rg * 8 + mt) * 32;
    unsigned* myFlag = line + p;
    float* scr = (float*)(smem + (size_t)64 * ldsRow);  // [mt][g][64 lanes] f4, contiguous

    float cr[4] = {0.f, 0.f, 0.f, 0.f};
    bool dead = false;

    auto ldB = [&](int kbyte, int rrow) -> h8 {
        return *(const h8*)(smem + rrow * ldsRow + (kbyte ^ ((rrow & 7) << 4)));
    };

    auto xpart = [&](int t, f4 (&C)[4]) {
        #pragma unroll
        for (int g = 0; g < 4; ++g) C[g] = (f4){0.f, 0.f, 0.f, 0.f};
        const _Float16* ap = src + (size_t)t * Bd * Din + (size_t)arow * Din;
        for (int ks = xlo; ks < xhi; ++ks) {
            const int kb = (ks << 5) + (kq << 3);
            const int kbyte = kb << 1;
            h8 bf0 = ldB(kbyte, colsel);
            h8 bf1 = ldB(kbyte, 16 + colsel);
            h8 bf2 = ldB(kbyte, 32 + colsel);
            h8 bf3 = ldB(kbyte, 48 + colsel);
            h8 a0 = *(const h8*)(ap + kb);
            MF(C[0], a0, bf0); MF(C[1], a0, bf1); MF(C[2], a0, bf2); MF(C[3], a0, bf3);
        }
    };

    auto hpart = [&](int t, f4 (&C)[4]) {
        const _Float16* ap = dst + (size_t)(t - 1) * Bd * 512 + (size_t)arow * 512;
        #pragma unroll 4
        for (int ks = hlo; ks < hhi; ++ks) {
            const int kb = (ks << 5) + (kq << 3);
            const int kbyte = (Din + kb) << 1;
            h8 bf0 = ldB(kbyte, colsel);
            h8 bf1 = ldB(kbyte, 16 + colsel);
            h8 bf2 = ldB(kbyte, 32 + colsel);
            h8 bf3 = ldB(kbyte, 48 + colsel);
            h8 a0 = *(const h8*)(ap + kb);
            MF(C[0], a0, bf0); MF(C[1], a0, bf1); MF(C[2], a0, bf2); MF(C[3], a0, bf3);
        }
    };

    auto writeScr = [&](f4 (&C)[4]) {
        #pragma unroll
        for (int g = 0; g < 4; ++g)
            *(f4*)(scr + (size_t)((mt * 4 + g) * 64 + lane) * 4) = C[g];
    };

    auto finish = [&](int t, f4 (&C)[4]) {
        if constexpr (RED) {
            #pragma unroll
            for (int g = 0; g < 4; ++g)
                C[g] += *(const f4*)(scr + (size_t)((mt * 4 + g) * 64 + lane) * 4);
        }
        const size_t rb = (size_t)t * Bd + rowBase + mt * 16 + kq * 4;
        #pragma unroll
        for (int j = 0; j < 4; ++j) {
            const float gi = C[0][j] + bq0;
            const float gf = C[1][j] + bq1;
            const float gg = C[2][j] + bq2;
            const float go = C[3][j] + bq3;
            const float cc = sigf(gf) * cr[j] + sigf(gi) * tanhfast(gg);
            const float hh = sigf(go) * tanhfast(cc);
            cr[j] = cc;
            dst[(rb + j) * 512 + hcol] = (_Float16)hh;
        }
        vm0();
        if (lane == 0) fl_st(myFlag, (unsigned)(t + 1));
    };

    f4 accA[4], accB[4];
    if (busy) xpart(0, accA);

    #define DR_STEP(T, CUR, NXT)                                             \
    {                                                                        \
        if (busy && (T) > 0) {                                               \
            wait_flags(line, (unsigned)(T), lane, dead);                     \
            l1inv();                                                         \
            hpart((T), CUR);                                                 \
        }                                                                    \
        if constexpr (RED) {                                                 \
            if (busy && kh == 1) writeScr(CUR);                              \
            __syncthreads();                                                 \
        }                                                                    \
        if (busy && kh == 0) finish((T), CUR);                               \
        if (busy && (T) + 1 < Td) xpart((T) + 1, NXT);                       \
    }

    for (int t = 0; t < Td; t += 2) {
        DR_STEP(t, accA, accB)
        DR_STEP(t + 1, accB, accA)
    }
    #undef DR_STEP
}

// ---------------------------------------------------------------- persistent kernel

__global__ __launch_bounds__(TPB) void drnn_persist(
    const _Float16* __restrict__ seqX,
    _Float16* __restrict__ seq0,
    _Float16* __restrict__ seq1,
    _Float16* __restrict__ seq2,
    _Float16* __restrict__ seq3,
    const _Float16* __restrict__ Wprep,
    const float* __restrict__ biasSum,
    unsigned* __restrict__ syncc)
{
    extern __shared__ char smem[];
    const int tid = threadIdx.x;
    const int lane = tid & 63;
    const int wave = tid >> 6;

    // Self-assign (rg, p) from physical XCD so each row-group's 32 blocks share
    // one L2. 144KB LDS -> 1 block/CU; 256 blocks on 256 CUs -> exactly 32/XCD.
    // Counters live at dwords 512..960 (rounds 5-7 had them aliasing flags[0]).
    unsigned* s_flag = (unsigned*)smem;
    if (tid == 0) {
        unsigned xcc;
        asm volatile("s_getreg_b32 %0, hwreg(HW_REG_XCC_ID)" : "=s"(xcc));
        xcc &= 7u;
        unsigned slot = __hip_atomic_fetch_add(syncc + 512u + 64u * xcc, 1u,
                                               __ATOMIC_RELAXED, __HIP_MEMORY_SCOPE_AGENT);
        s_flag[0] = (xcc << 5) | (slot & 31u);
    }
    __syncthreads();
    const unsigned rgp = s_flag[0];
    __syncthreads();
    const int rg = rgp >> 5;     // == XCC_ID
    const int p = rgp & 31;      // col-group: h-cols [p*16, p*16+16)

    unsigned* cellCnt = syncc;               // dword 0
    unsigned* flags = syncc + 1024;          // 4 cells x (8rg x 8mt x 32q) dwords

    // cross-XCD cell barrier (3x total): leader verifies rg completion via flags,
    // then agent-scope release/acquire moves h data across XCD L2s.
    auto cell_barrier = [&](int cellIdx, unsigned TdPrev, int nMtPrev, unsigned* flagsPrev) {
        __syncthreads();
        if (p == 0 && tid < 32 * nMtPrev) {
            const unsigned* fp = flagsPrev + (rg * 8 + (tid >> 5)) * 32 + (tid & 31);
            poll_ge(fp, TdPrev);
        }
        __syncthreads();
        if (tid == 0) {
            if (p == 0)
                __hip_atomic_fetch_add(cellCnt, 1u, __ATOMIC_RELEASE, __HIP_MEMORY_SCOPE_AGENT);
            unsigned n = 0;
            while (__hip_atomic_load(cellCnt, __ATOMIC_RELAXED, __HIP_MEMORY_SCOPE_AGENT)
                   < (unsigned)(8 * cellIdx)) {
                __builtin_amdgcn_s_sleep(2);
                if (++n > SPIN_BOUND) break;
            }
            (void)__hip_atomic_load(cellCnt, __ATOMIC_ACQUIRE, __HIP_MEMORY_SCOPE_AGENT);
        }
        __syncthreads();
        l1inv();
    };

    run_cell<0>(seqX, seq0, Wprep, biasSum, flags + 0 * 2048, smem, p, tid, lane, wave, rg);
    cell_barrier(1, 256u, 1, flags + 0 * 2048);
    run_cell<1>(seq0, seq1, Wprep + (size_t)2048 * 640, biasSum, flags + 1 * 2048, smem, p, tid, lane, wave, rg);
    cell_barrier(2, 128u, 2, flags + 1 * 2048);
    run_cell<2>(seq1, seq2, Wprep + (size_t)2048 * (640 + 1024), biasSum, flags + 2 * 2048, smem, p, tid, lane, wave, rg);
    cell_barrier(3, 64u, 4, flags + 2 * 2048);
    run_cell<3>(seq2, seq3, Wprep + (size_t)2048 * (640 + 2048), biasSum, flags + 3 * 2048, smem, p, tid, lane, wave, rg);
}

// ---------------------------------------------------------------- head

__global__ __launch_bounds__(256) void head_kernel(
    const _Float16* __restrict__ seq1,
    const _Float16* __restrict__ seq3,
    const _Float16* __restrict__ mlpW16,
    const float* __restrict__ mlp_b,
    const _Float16* __restrict__ adpW16,
    const float* __restrict__ adp_b,
    float* __restrict__ out)
{
    extern __shared__ char smem[];   // y1 tile [64][512] fp16, XOR-swizzled
    const int tid = threadIdx.x;
    const int lane = tid & 63, wave = tid >> 6;
    const int colsel = lane & 15, kq = lane >> 4;
    const size_t row0 = (size_t)blockIdx.x * 64 + wave * 16;

    h8 aR[16];
    {
        const size_t ar = (row0 + colsel) * 512;
        #pragma unroll
        for (int ks = 0; ks < 16; ++ks) {
            const int kb = ks * 32 + kq * 8;
            h8 a1 = *(const h8*)(seq1 + ar + kb);
            h8 a3 = *(const h8*)(seq3 + ar + kb);
            aR[ks] = a1 + a3;
        }
    }
    for (int nt = 0; nt < 32; ++nt) {
        f4 acc = {0.f, 0.f, 0.f, 0.f};
        const int brow = nt * 16 + colsel;
        #pragma unroll
        for (int ks = 0; ks < 16; ++ks) {
            const int kb = ks * 32 + kq * 8;
            h8 b = *(const h8*)(mlpW16 + (size_t)brow * 512 + kb);
            acc = __builtin_amdgcn_mfma_f32_16x16x32_f16(aR[ks], b, acc, 0, 0, 0);
        }
        const int n = nt * 16 + colsel;
        const float bn = mlp_b[n];
        const int lrow0 = wave * 16 + kq * 4;
        #pragma unroll
        for (int j = 0; j < 4; ++j) {
            const float y = tanhfast(acc[j] + bn);
            const int row = lrow0 + j;
            *(_Float16*)(smem + row * 1024 + ((n * 2) ^ ((row & 7) << 4))) = (_Float16)y;
        }
    }
    __syncthreads();
    f4 acc0 = {0.f,0.f,0.f,0.f}, acc1 = {0.f,0.f,0.f,0.f}, acc2 = {0.f,0.f,0.f,0.f};
    const int arow = wave * 16 + colsel;
    #pragma unroll
    for (int ks = 0; ks < 16; ++ks) {
        const int kb = ks * 32 + kq * 8;
        h8 a = *(const h8*)(smem + arow * 1024 + ((kb * 2) ^ ((arow & 7) << 4)));
        h8 b0 = *(const h8*)(adpW16 + (size_t)(colsel) * 512 + kb);
        h8 b1 = *(const h8*)(adpW16 + (size_t)(16 + colsel) * 512 + kb);
        h8 b2 = *(const h8*)(adpW16 + (size_t)(32 + colsel) * 512 + kb);
        acc0 = __builtin_amdgcn_mfma_f32_16x16x32_f16(a, b0, acc0, 0, 0, 0);
        acc1 = __builtin_amdgcn_mfma_f32_16x16x32_f16(a, b1, acc1, 0, 0, 0);
        acc2 = __builtin_amdgcn_mfma_f32_16x16x32_f16(a, b2, acc2, 0, 0, 0);
    }
    const size_t orow0 = row0 + kq * 4;
    #pragma unroll
    for (int j = 0; j < 4; ++j) {
        out[(orow0 + j) * 48 + colsel]      = acc0[j] + adp_b[colsel];
        out[(orow0 + j) * 48 + 16 + colsel] = acc1[j] + adp_b[16 + colsel];
        out[(orow0 + j) * 48 + 32 + colsel] = acc2[j] + adp_b[32 + colsel];
    }
}

// ---------------------------------------------------------------- launch

extern "C" void kernel_launch(void* const* d_in, const int* in_sizes, int n_in,
                              void* d_out, int out_size, void* d_ws, size_t ws_size,
                              hipStream_t stream)
{
    (void)in_sizes; (void)n_in; (void)out_size; (void)ws_size;
    const float* input = (const float*)d_in[0];
    const float* Wih[4]; const float* Whh[4]; const float* Bih[4]; const float* Bhh[4];
    for (int i = 0; i < 4; ++i) {
        Wih[i] = (const float*)d_in[1 + 4 * i];
        Whh[i] = (const float*)d_in[2 + 4 * i];
        Bih[i] = (const float*)d_in[3 + 4 * i];
        Bhh[i] = (const float*)d_in[4 + 4 * i];
    }
    const float* mlpw = (const float*)d_in[17];
    const float* mlpb = (const float*)d_in[18];
    const float* adpw = (const float*)d_in[19];
    const float* adpb = (const float*)d_in[20];
    float* out = (float*)d_out;

    char* ws = (char*)d_ws;
    size_t off = 0;
    auto alloc = [&](size_t bytes) -> char* {
        char* ptr = ws + off;
        off += (bytes + 255) & ~(size_t)255;
        return ptr;
    };
    unsigned* syncc   = (unsigned*)alloc(40960);
    _Float16* seqX    = (_Float16*)alloc((size_t)32768 * 128 * 2);
    _Float16* seq0    = (_Float16*)alloc((size_t)32768 * 512 * 2);
    _Float16* seq1    = (_Float16*)alloc((size_t)32768 * 512 * 2);
    _Float16* seq2    = (_Float16*)alloc((size_t)32768 * 512 * 2);
    _Float16* seq3    = (_Float16*)alloc((size_t)32768 * 512 * 2);
    _Float16* Wprep   = (_Float16*)alloc((size_t)2048 * 3712 * 2);
    float*    biasSum = (float*)alloc(8192 * 4);
    _Float16* mlpW16  = (_Float16*)alloc((size_t)262144 * 2);
    _Float16* adpW16  = (_Float16*)alloc((size_t)24576 * 2);

    hipMemsetAsync(syncc, 0, 40960, stream);
    prep_conv<<<2048, 256, 0, stream>>>(input, mlpw, adpw, seqX, mlpW16, adpW16);
    prep_bias<<<32, 256, 0, stream>>>(Bih[0], Bhh[0], Bih[1], Bhh[1],
                                      Bih[2], Bhh[2], Bih[3], Bhh[3], biasSum);
    prep_w<<<4096, 256, 0, stream>>>(Wih[0], Whh[0], Wih[1], Whh[1],
                                     Wih[2], Whh[2], Wih[3], Whh[3], Wprep);

    hipFuncSetAttribute((const void*)drnn_persist,
                        hipFuncAttributeMaxDynamicSharedMemorySize, 147456);
    hipFuncSetAttribute((const void*)head_kernel,
                        hipFuncAttributeMaxDynamicSharedMemorySize, 65536);

    drnn_persist<<<NBLK, TPB, 147456, stream>>>(seqX, seq0, seq1, seq2, seq3,
                                                Wprep, biasSum, syncc);
    head_kernel<<<512, 256, 65536, stream>>>(seq1, seq3, mlpW16, mlpb, adpW16, adpb, out);
}

// Round 9
// 2572.432 us; speedup vs baseline: 1.2686x; 1.0741x over previous
//
#include <hip/hip_runtime.h>

#define TPB 512
#define NBLK 256
#define SPIN_BOUND (1u << 21)
#define LDS_SPIN_BOUND (1u << 16)

typedef _Float16 h8 __attribute__((ext_vector_type(8)));
typedef float f4 __attribute__((ext_vector_type(4)));

__device__ __forceinline__ float sigf(float x) { return 1.f / (1.f + __expf(-x)); }
__device__ __forceinline__ float tanhfast(float x) { return 2.f / (1.f + __expf(-2.f * x)) - 1.f; }

#define MF(acc, a, b) acc = __builtin_amdgcn_mfma_f32_16x16x32_f16(a, b, acc, 0, 0, 0)

__device__ __forceinline__ void vm0() { asm volatile("s_waitcnt vmcnt(0)" ::: "memory"); }
__device__ __forceinline__ void l1inv() { asm volatile("buffer_inv sc0" ::: "memory"); }

// Proven flag fabric (r7/r8): producer = plain store after vmcnt(0) (write-through
// L1 -> shared XCD L2); consumer = buffer_inv sc0 + volatile load per poll.
// h/x DATA needs no invalidation at all: addresses are unique per step (buffers
// indexed by t), so consumer L1 can never hold a stale copy.
__device__ __forceinline__ bool poll_ge(const unsigned* p, unsigned target) {
    const volatile unsigned* vp = (const volatile unsigned*)p;
    unsigned n = 0;
    for (;;) {
        l1inv();
        if (*vp >= target) return true;
        __builtin_amdgcn_s_sleep(1);
        if (++n > SPIN_BOUND) return false;
    }
}

// ---------------------------------------------------------------- prep kernels

__global__ void prep_conv(const float* __restrict__ in, const float* __restrict__ mlpw,
                          const float* __restrict__ adpw,
                          _Float16* __restrict__ seqX, _Float16* __restrict__ mlpW16,
                          _Float16* __restrict__ adpW16)
{
    const int NIN = 256 * 128 * 128;
    const int NM = 512 * 512;
    const int NA = 48 * 512;
    int i = blockIdx.x * blockDim.x + threadIdx.x;
    const int stride = gridDim.x * blockDim.x;
    for (; i < NIN + NM + NA; i += stride) {
        if (i < NIN) seqX[i] = (_Float16)in[i];
        else if (i < NIN + NM) mlpW16[i - NIN] = (_Float16)mlpw[i - NIN];
        else adpW16[i - NIN - NM] = (_Float16)adpw[i - NIN - NM];
    }
}

__global__ void prep_bias(const float* __restrict__ a0, const float* __restrict__ b0,
                          const float* __restrict__ a1, const float* __restrict__ b1,
                          const float* __restrict__ a2, const float* __restrict__ b2,
                          const float* __restrict__ a3, const float* __restrict__ b3,
                          float* __restrict__ biasSum)
{
    int i = blockIdx.x * blockDim.x + threadIdx.x;
    if (i >= 8192) return;
    const int c = i >> 11, j = i & 2047;
    const float* A = (c == 0) ? a0 : (c == 1) ? a1 : (c == 2) ? a2 : a3;
    const float* B = (c == 0) ? b0 : (c == 1) ? b1 : (c == 2) ? b2 : b3;
    biasSum[i] = A[j] + B[j];
}

// Wprep layout per cell: [p=32 col-groups][64 rows][K] fp16
__global__ void prep_w(const float* __restrict__ wih0, const float* __restrict__ whh0,
                       const float* __restrict__ wih1, const float* __restrict__ whh1,
                       const float* __restrict__ wih2, const float* __restrict__ whh2,
                       const float* __restrict__ wih3, const float* __restrict__ whh3,
                       _Float16* __restrict__ Wprep)
{
    const size_t N0 = (size_t)2048 * 640;
    const size_t N1 = (size_t)2048 * 1024;
    const size_t total = N0 + 3 * N1;
    size_t i = (size_t)blockIdx.x * blockDim.x + threadIdx.x;
    const size_t stride = (size_t)gridDim.x * blockDim.x;
    for (; i < total; i += stride) {
        int cell; size_t off;
        if (i < N0) { cell = 0; off = i; }
        else { cell = 1 + (int)((i - N0) / N1); off = (i - N0) % N1; }
        const int K = cell ? 1024 : 640;
        const int Din = cell ? 512 : 128;
        const int k = (int)(off % K);
        const int rowIdx = (int)(off / K);
        const int p = rowIdx >> 6;
        const int row64 = rowIdx & 63;
        const int q = row64 >> 4;
        const int gRow = q * 512 + p * 16 + (row64 & 15);
        const float* wih = (cell == 0) ? wih0 : (cell == 1) ? wih1 : (cell == 2) ? wih2 : wih3;
        const float* whh = (cell == 0) ? whh0 : (cell == 1) ? whh1 : (cell == 2) ? whh2 : whh3;
        const float v = (k < Din) ? wih[(size_t)gRow * Din + k]
                                  : whh[(size_t)gRow * 512 + (k - Din)];
        Wprep[i] = (_Float16)v;
    }
}

// ---------------------------------------------------------------- per-cell LSTM
// 8 waves/block. Cells 0-2: m-tile owned by a wave pair split over K (kh=0/1);
// kh=1 writes partials to LDS scratch, barrier, kh=0 reduces+epilogs+flags.
// Cell 3: 8 m-tiles, 1 per wave, full K.
// Flags: strided 8 dwords (32B) apart, per (rg,mt) line of 32.
// Cells 0/1: dedicated poller wave + LDS gen broadcast (no inv on compute waves).

template<int CELL>
__device__ __forceinline__ void run_cell(
    const _Float16* __restrict__ src, _Float16* __restrict__ dst,
    const _Float16* __restrict__ wbase, const float* __restrict__ biasSum,
    unsigned* __restrict__ cellFlags, char* smem,
    const int p, const int tid, const int lane, const int wave, const int rg)
{
    constexpr int Din = (CELL == 0) ? 128 : 512;
    constexpr int K = Din + 512;
    constexpr int Bd = 128 << CELL;
    constexpr int Td = 256 >> CELL;
    constexpr int r = Bd >> 3;
    constexpr int nMt = r >> 4;            // 1,2,4,8
    constexpr int ldsRow = K * 2;
    constexpr int NKX = Din >> 5;          // 4 or 16
    constexpr bool RED = (CELL < 3);
    constexpr int NXW = RED ? (NKX / 2) : NKX;   // x ks per wave: 2,8,8,16
    constexpr int pollW = (2 * nMt < 8) ? (2 * nMt) : -1;

    const int colsel = lane & 15;
    const int kq = lane >> 4;
    const int rowBase = rg * r;

    volatile unsigned* ldsGen = (volatile unsigned*)(smem + 64 * ldsRow + 16384);

    // stage W slice (64 rows x K fp16) into LDS, XOR-swizzled (all 512 threads)
    {
        const _Float16* wsl = wbase + (size_t)p * 64 * K;
        constexpr int kcN = K >> 3;
        #pragma unroll 2
        for (int i = tid; i < 64 * kcN; i += TPB) {
            const int row = i / kcN;
            const int kc = i - row * kcN;
            h8 v = *(const h8*)(wsl + (size_t)row * K + (kc << 3));
            *(h8*)(smem + row * ldsRow + ((kc << 4) ^ ((row & 7) << 4))) = v;
        }
        if (tid == 0) *ldsGen = 0u;
    }
    __syncthreads();   // W staged, ldsGen init

    const int mt = RED ? (wave >> 1) : wave;
    const int kh = RED ? (wave & 1) : 0;
    const bool busy = RED ? (wave < 2 * nMt) : true;

    const int xlo = (RED && kh) ? (NKX / 2) : 0;
    const int hlo = (RED && kh) ? 8 : 0;

    const float bq0 = biasSum[CELL * 2048 + 0 * 512 + p * 16 + colsel];
    const float bq1 = biasSum[CELL * 2048 + 1 * 512 + p * 16 + colsel];
    const float bq2 = biasSum[CELL * 2048 + 2 * 512 + p * 16 + colsel];
    const float bq3 = biasSum[CELL * 2048 + 3 * 512 + p * 16 + colsel];

    const int arow = rowBase + mt * 16 + colsel;
    const int hcol = p * 16 + colsel;

    unsigned* myFlag = cellFlags + (rg * 8 + mt) * 256 + p * 8;
    float* scr = (float*)(smem + (size_t)64 * ldsRow);

    float cr[4] = {0.f, 0.f, 0.f, 0.f};
    bool dead = false;
    h8 xr[NXW];
    h8 hr0[8];

    auto ldB = [&](int kbyte, int rrow) -> h8 {
        return *(const h8*)(smem + rrow * ldsRow + (kbyte ^ ((rrow & 7) << 4)));
    };

    // dedicated poller: waits all nMt lines (pairs of lines across lane halves)
    auto poll_multi = [&](unsigned target) -> bool {
        const int q = lane & 31;
        #pragma unroll
        for (int l0 = 0; l0 < nMt; l0 += 2) {
            int li = l0 + (lane >> 5); if (li >= nMt) li = nMt - 1;
            const volatile unsigned* fp =
                (const volatile unsigned*)(cellFlags + (rg * 8 + li) * 256 + q * 8);
            unsigned n = 0;
            for (;;) {
                l1inv();
                if (__all((int)(*fp >= target))) break;
                if (++n > SPIN_BOUND) return false;
            }
        }
        return true;
    };
    // self-poll of own mt line (cells 2/3)
    auto poll_own = [&](unsigned target) -> bool {
        const volatile unsigned* fp =
            (const volatile unsigned*)(cellFlags + (rg * 8 + mt) * 256 + (lane & 31) * 8);
        unsigned n = 0;
        for (;;) {
            l1inv();
            if (__all((int)(*fp >= target))) break;
            if (++n > SPIN_BOUND) return false;
        }
        return true;
    };
    auto spin_gen = [&](unsigned target) {
        unsigned n = 0;
        while (*ldsGen < target) { if (++n > LDS_SPIN_BOUND) break; }
    };

    auto x_issue = [&](int t) {
        const _Float16* ap = src + (size_t)t * Bd * Din + (size_t)arow * Din + (kq << 3);
        #pragma unroll
        for (int i = 0; i < NXW; ++i)
            xr[i] = *(const h8*)(ap + ((xlo + i) << 5));
    };
    auto x_compute = [&](f4 (&C)[4]) {
        #pragma unroll
        for (int g = 0; g < 4; ++g) C[g] = (f4){0.f, 0.f, 0.f, 0.f};
        #pragma unroll
        for (int i = 0; i < NXW; ++i) {
            const int kbyte = (((xlo + i) << 5) + (kq << 3)) << 1;
            h8 bf0 = ldB(kbyte, colsel);
            h8 bf1 = ldB(kbyte, 16 + colsel);
            h8 bf2 = ldB(kbyte, 32 + colsel);
            h8 bf3 = ldB(kbyte, 48 + colsel);
            MF(C[0], xr[i], bf0); MF(C[1], xr[i], bf1);
            MF(C[2], xr[i], bf2); MF(C[3], xr[i], bf3);
        }
    };
    auto h_issue0 = [&](int t) {
        const _Float16* ap = dst + (size_t)(t - 1) * Bd * 512 + (size_t)arow * 512 + (kq << 3);
        #pragma unroll
        for (int i = 0; i < 8; ++i)
            hr0[i] = *(const h8*)(ap + ((hlo + i) << 5));
    };
    auto h_compute = [&](int t, f4 (&C)[4]) {
        #pragma unroll
        for (int i = 0; i < 8; ++i) {
            const int kbyte = (Din + ((hlo + i) << 5) + (kq << 3)) << 1;
            h8 bf0 = ldB(kbyte, colsel);
            h8 bf1 = ldB(kbyte, 16 + colsel);
            h8 bf2 = ldB(kbyte, 32 + colsel);
            h8 bf3 = ldB(kbyte, 48 + colsel);
            MF(C[0], hr0[i], bf0); MF(C[1], hr0[i], bf1);
            MF(C[2], hr0[i], bf2); MF(C[3], hr0[i], bf3);
        }
        if constexpr (!RED) {   // cell3: second batch of 8 ks
            const _Float16* ap = dst + (size_t)(t - 1) * Bd * 512 + (size_t)arow * 512 + (kq << 3);
            h8 hr1[8];
            #pragma unroll
            for (int i = 0; i < 8; ++i)
                hr1[i] = *(const h8*)(ap + ((8 + i) << 5));
            #pragma unroll
            for (int i = 0; i < 8; ++i) {
                const int kbyte = (Din + ((8 + i) << 5) + (kq << 3)) << 1;
                h8 bf0 = ldB(kbyte, colsel);
                h8 bf1 = ldB(kbyte, 16 + colsel);
                h8 bf2 = ldB(kbyte, 32 + colsel);
                h8 bf3 = ldB(kbyte, 48 + colsel);
                MF(C[0], hr1[i], bf0); MF(C[1], hr1[i], bf1);
                MF(C[2], hr1[i], bf2); MF(C[3], hr1[i], bf3);
            }
        }
    };
    auto writeScr = [&](f4 (&C)[4]) {
        #pragma unroll
        for (int g = 0; g < 4; ++g)
            *(f4*)(scr + (size_t)((mt * 4 + g) * 64 + lane) * 4) = C[g];
    };
    auto finish = [&](int t, f4 (&C)[4]) {
        if constexpr (RED) {
            #pragma unroll
            for (int g = 0; g < 4; ++g)
                C[g] += *(const f4*)(scr + (size_t)((mt * 4 + g) * 64 + lane) * 4);
        }
        const size_t rb = (size_t)t * Bd + rowBase + mt * 16 + kq * 4;
        #pragma unroll
        for (int j = 0; j < 4; ++j) {
            const float gi = C[0][j] + bq0;
            const float gf = C[1][j] + bq1;
            const float gg = C[2][j] + bq2;
            const float go = C[3][j] + bq3;
            const float cc = sigf(gf) * cr[j] + sigf(gi) * tanhfast(gg);
            const float hh = sigf(go) * tanhfast(cc);
            cr[j] = cc;
            dst[(rb + j) * 512 + hcol] = (_Float16)hh;
        }
        vm0();
        if (lane == 0) *(volatile unsigned*)myFlag = (unsigned)(t + 1);
    };

    f4 acc[4];
    if (busy) x_issue(0);

    for (int t = 0; t < Td; ++t) {
        if (t > 0) {
            if constexpr (pollW >= 0) {
                if (wave == pollW) {
                    if (!dead) dead = !poll_multi((unsigned)t);
                    if (lane == 0) *ldsGen = (unsigned)t;
                } else if (busy) {
                    spin_gen((unsigned)t);
                }
            } else {
                if (!dead) dead = !poll_own((unsigned)t);
            }
            if (busy) h_issue0(t);
        }
        if (busy) {
            x_compute(acc);
            if (t > 0) h_compute(t, acc);
        }
        if constexpr (RED) {
            if (busy && kh == 1) writeScr(acc);
            __syncthreads();
        }
        if (busy && kh == 0) finish(t, acc);
        if (busy && t + 1 < Td) x_issue(t + 1);
    }
}

// ---------------------------------------------------------------- persistent kernel

__global__ __launch_bounds__(TPB) void drnn_persist(
    const _Float16* __restrict__ seqX,
    _Float16* __restrict__ seq0,
    _Float16* __restrict__ seq1,
    _Float16* __restrict__ seq2,
    _Float16* __restrict__ seq3,
    const _Float16* __restrict__ Wprep,
    const float* __restrict__ biasSum,
    unsigned* __restrict__ syncc)
{
    extern __shared__ char smem[];
    const int tid = threadIdx.x;
    const int lane = tid & 63;
    const int wave = tid >> 6;

    // Self-assign (rg, p) from physical XCD so each row-group's 32 blocks share
    // one L2. ~148KB LDS -> 1 block/CU; 256 blocks on 256 CUs -> exactly 32/XCD.
    unsigned* s_flag = (unsigned*)smem;
    if (tid == 0) {
        unsigned xcc;
        asm volatile("s_getreg_b32 %0, hwreg(HW_REG_XCC_ID)" : "=s"(xcc));
        xcc &= 7u;
        unsigned slot = __hip_atomic_fetch_add(syncc + 512u + 64u * xcc, 1u,
                                               __ATOMIC_RELAXED, __HIP_MEMORY_SCOPE_AGENT);
        s_flag[0] = (xcc << 5) | (slot & 31u);
    }
    __syncthreads();
    const unsigned rgp = s_flag[0];
    __syncthreads();
    const int rg = rgp >> 5;     // == XCC_ID
    const int p = rgp & 31;      // col-group: h-cols [p*16, p*16+16)

    unsigned* cellCnt = syncc;                 // dword 0
    unsigned* flags = syncc + 1024;            // 4 cells x (8rg x 8mt x 32q x 8-stride)

    auto cell_barrier = [&](int cellIdx, unsigned TdPrev, int nMtPrev, unsigned* flagsPrev) {
        __syncthreads();
        if (p == 0 && tid < 32 * nMtPrev) {
            const unsigned* fp = flagsPrev + (rg * 8 + (tid >> 5)) * 256 + (tid & 31) * 8;
            poll_ge(fp, TdPrev);
        }
        __syncthreads();
        if (tid == 0) {
            if (p == 0)
                __hip_atomic_fetch_add(cellCnt, 1u, __ATOMIC_RELEASE, __HIP_MEMORY_SCOPE_AGENT);
            unsigned n = 0;
            while (__hip_atomic_load(cellCnt, __ATOMIC_RELAXED, __HIP_MEMORY_SCOPE_AGENT)
                   < (unsigned)(8 * cellIdx)) {
                __builtin_amdgcn_s_sleep(2);
                if (++n > SPIN_BOUND) break;
            }
            (void)__hip_atomic_load(cellCnt, __ATOMIC_ACQUIRE, __HIP_MEMORY_SCOPE_AGENT);
        }
        __syncthreads();
        l1inv();
    };

    run_cell<0>(seqX, seq0, Wprep, biasSum, flags + 0 * 16384, smem, p, tid, lane, wave, rg);
    cell_barrier(1, 256u, 1, flags + 0 * 16384);
    run_cell<1>(seq0, seq1, Wprep + (size_t)2048 * 640, biasSum, flags + 1 * 16384, smem, p, tid, lane, wave, rg);
    cell_barrier(2, 128u, 2, flags + 1 * 16384);
    run_cell<2>(seq1, seq2, Wprep + (size_t)2048 * (640 + 1024), biasSum, flags + 2 * 16384, smem, p, tid, lane, wave, rg);
    cell_barrier(3, 64u, 4, flags + 2 * 16384);
    run_cell<3>(seq2, seq3, Wprep + (size_t)2048 * (640 + 2048), biasSum, flags + 3 * 16384, smem, p, tid, lane, wave, rg);
}

// ---------------------------------------------------------------- head

__global__ __launch_bounds__(256) void head_kernel(
    const _Float16* __restrict__ seq1,
    const _Float16* __restrict__ seq3,
    const _Float16* __restrict__ mlpW16,
    const float* __restrict__ mlp_b,
    const _Float16* __restrict__ adpW16,
    const float* __restrict__ adp_b,
    float* __restrict__ out)
{
    extern __shared__ char smem[];   // y1 tile [64][512] fp16, XOR-swizzled
    const int tid = threadIdx.x;
    const int lane = tid & 63, wave = tid >> 6;
    const int colsel = lane & 15, kq = lane >> 4;
    const size_t row0 = (size_t)blockIdx.x * 64 + wave * 16;

    h8 aR[16];
    {
        const size_t ar = (row0 + colsel) * 512;
        #pragma unroll
        for (int ks = 0; ks < 16; ++ks) {
            const int kb = ks * 32 + kq * 8;
            h8 a1 = *(const h8*)(seq1 + ar + kb);
            h8 a3 = *(const h8*)(seq3 + ar + kb);
            aR[ks] = a1 + a3;
        }
    }
    for (int nt = 0; nt < 32; ++nt) {
        f4 acc = {0.f, 0.f, 0.f, 0.f};
        const int brow = nt * 16 + colsel;
        #pragma unroll
        for (int ks = 0; ks < 16; ++ks) {
            const int kb = ks * 32 + kq * 8;
            h8 b = *(const h8*)(mlpW16 + (size_t)brow * 512 + kb);
            acc = __builtin_amdgcn_mfma_f32_16x16x32_f16(aR[ks], b, acc, 0, 0, 0);
        }
        const int n = nt * 16 + colsel;
        const float bn = mlp_b[n];
        const int lrow0 = wave * 16 + kq * 4;
        #pragma unroll
        for (int j = 0; j < 4; ++j) {
            const float y = tanhfast(acc[j] + bn);
            const int row = lrow0 + j;
            *(_Float16*)(smem + row * 1024 + ((n * 2) ^ ((row & 7) << 4))) = (_Float16)y;
        }
    }
    __syncthreads();
    f4 acc0 = {0.f,0.f,0.f,0.f}, acc1 = {0.f,0.f,0.f,0.f}, acc2 = {0.f,0.f,0.f,0.f};
    const int arow = wave * 16 + colsel;
    #pragma unroll
    for (int ks = 0; ks < 16; ++ks) {
        const int kb = ks * 32 + kq * 8;
        h8 a = *(const h8*)(smem + arow * 1024 + ((kb * 2) ^ ((arow & 7) << 4)));
        h8 b0 = *(const h8*)(adpW16 + (size_t)(colsel) * 512 + kb);
        h8 b1 = *(const h8*)(adpW16 + (size_t)(16 + colsel) * 512 + kb);
        h8 b2 = *(const h8*)(adpW16 + (size_t)(32 + colsel) * 512 + kb);
        acc0 = __builtin_amdgcn_mfma_f32_16x16x32_f16(a, b0, acc0, 0, 0, 0);
        acc1 = __builtin_amdgcn_mfma_f32_16x16x32_f16(a, b1, acc1, 0, 0, 0);
        acc2 = __builtin_amdgcn_mfma_f32_16x16x32_f16(a, b2, acc2, 0, 0, 0);
    }
    const size_t orow0 = row0 + kq * 4;
    #pragma unroll
    for (int j = 0; j < 4; ++j) {
        out[(orow0 + j) * 48 + colsel]      = acc0[j] + adp_b[colsel];
        out[(orow0 + j) * 48 + 16 + colsel] = acc1[j] + adp_b[16 + colsel];
        out[(orow0 + j) * 48 + 32 + colsel] = acc2[j] + adp_b[32 + colsel];
    }
}

// ---------------------------------------------------------------- launch

extern "C" void kernel_launch(void* const* d_in, const int* in_sizes, int n_in,
                              void* d_out, int out_size, void* d_ws, size_t ws_size,
                              hipStream_t stream)
{
    (void)in_sizes; (void)n_in; (void)out_size; (void)ws_size;
    const float* input = (const float*)d_in[0];
    const float* Wih[4]; const float* Whh[4]; const float* Bih[4]; const float* Bhh[4];
    for (int i = 0; i < 4; ++i) {
        Wih[i] = (const float*)d_in[1 + 4 * i];
        Whh[i] = (const float*)d_in[2 + 4 * i];
        Bih[i] = (const float*)d_in[3 + 4 * i];
        Bhh[i] = (const float*)d_in[4 + 4 * i];
    }
    const float* mlpw = (const float*)d_in[17];
    const float* mlpb = (const float*)d_in[18];
    const float* adpw = (const float*)d_in[19];
    const float* adpb = (const float*)d_in[20];
    float* out = (float*)d_out;

    char* ws = (char*)d_ws;
    size_t off = 0;
    auto alloc = [&](size_t bytes) -> char* {
        char* ptr = ws + off;
        off += (bytes + 255) & ~(size_t)255;
        return ptr;
    };
    const size_t SYNC_BYTES = (1024 + 4 * 16384) * 4;   // 266,240 B
    unsigned* syncc   = (unsigned*)alloc(SYNC_BYTES);
    _Float16* seqX    = (_Float16*)alloc((size_t)32768 * 128 * 2);
    _Float16* seq0    = (_Float16*)alloc((size_t)32768 * 512 * 2);
    _Float16* seq1    = (_Float16*)alloc((size_t)32768 * 512 * 2);
    _Float16* seq2    = (_Float16*)alloc((size_t)32768 * 512 * 2);
    _Float16* seq3    = (_Float16*)alloc((size_t)32768 * 512 * 2);
    _Float16* Wprep   = (_Float16*)alloc((size_t)2048 * 3712 * 2);
    float*    biasSum = (float*)alloc(8192 * 4);
    _Float16* mlpW16  = (_Float16*)alloc((size_t)262144 * 2);
    _Float16* adpW16  = (_Float16*)alloc((size_t)24576 * 2);

    hipMemsetAsync(syncc, 0, SYNC_BYTES, stream);
    prep_conv<<<2048, 256, 0, stream>>>(input, mlpw, adpw, seqX, mlpW16, adpW16);
    prep_bias<<<32, 256, 0, stream>>>(Bih[0], Bhh[0], Bih[1], Bhh[1],
                                      Bih[2], Bhh[2], Bih[3], Bhh[3], biasSum);
    prep_w<<<4096, 256, 0, stream>>>(Wih[0], Whh[0], Wih[1], Whh[1],
                                     Wih[2], Whh[2], Wih[3], Whh[3], Wprep);

    hipFuncSetAttribute((const void*)drnn_persist,
                        hipFuncAttributeMaxDynamicSharedMemorySize, 148224);
    hipFuncSetAttribute((const void*)head_kernel,
                        hipFuncAttributeMaxDynamicSharedMemorySize, 65536);

    drnn_persist<<<NBLK, TPB, 148224, stream>>>(seqX, seq0, seq1, seq2, seq3,
                                                Wprep, biasSum, syncc);
    head_kernel<<<512, 256, 65536, stream>>>(seq1, seq3, mlpW16, mlpb, adpW16, adpb, out);
}